// Round 7
// baseline (352.372 us; speedup 1.0000x reference)
//
#include <hip/hip_runtime.h>

// Photonic layer: U = product of 2016 MZI 2x2 rotations (Reck mesh), then
// out = x @ U.T (complex), then tiny first-order Kerr phase rotation.
//
// R14: FUSION. Delta-accounting R9/R12/R13 shows a consistent ~106us of
// non-kernel time per iteration for the two-dispatch graph vs ~23us for
// R7's single dispatch => ~83us fixed cost for the extra node, now the
// largest term (apply ~70us, build ~55us). This round fuses build+apply
// into ONE kernel:
//  - first-arriving block (atomic ticket => guaranteed resident, safe under
//    undefined dispatch order) builds U with R13's verified structure
//    (4 wave-parallel 16-layer segment chains in regs; combines
//    U = S3*(S2*(S1*S0)) via two 32KB LDS regions + S3 spilled through the
//    not-yet-written W workspace region);
//  - builder publishes W via agent-scope release (buffer_wbl2), readers
//    spin on the flag with s_sleep and agent-scope acquire (buffer_inv) --
//    this replaces the implicit inter-dispatch cache flush across
//    non-coherent XCD L2s;
//  - apply body byte-identical to R12/R13-verified math, + row clamping so
//    no tail kernel is needed.
// Fallback (no/small workspace): R13 build -> g_U_fallback + VALU tail.

#define PSIZE 64
#define N_PHASES 2016
#define NLAYER 63
#define LOSS_AMP 0.99426007f
#define NL_COEFF 2.6e-17f

#define WSPLIT_BYTES (4 * PSIZE * PSIZE * 2)  // 32 KB: Urh,Url,Uih,Uil bf16
#define CTRL_BYTES 256
#define FUSED_WS_NEED (CTRL_BYTES + WSPLIT_BYTES)

typedef __attribute__((ext_vector_type(8))) short sh8;    // 8 bf16 (4 VGPR)
typedef __attribute__((ext_vector_type(4))) float f32x4;  // MFMA C/D

__device__ __align__(16) float g_U_fallback[2 * PSIZE * PSIZE];

__device__ inline unsigned short f32_to_bf16_rn(float f) {
  unsigned int u = __float_as_uint(f);
  u += 0x7fffu + ((u >> 16) & 1u);   // round to nearest even
  return (unsigned short)(u >> 16);
}
__device__ inline float bf16_to_f32(unsigned short h) {
  return __uint_as_float(((unsigned int)h) << 16);
}
__device__ inline float rdlane(float v, int l) {  // compile-time lane
  return __int_as_float(__builtin_amdgcn_readlane(__float_as_int(v), l));
}
__device__ inline unsigned pkbf16(float a, float b) {
  unsigned r;
  asm("v_cvt_pk_bf16_f32 %0, %1, %2" : "=v"(r) : "v"(a), "v"(b));
  return r;
}
__device__ inline float lo16f(unsigned u) { return __uint_as_float(u << 16); }
__device__ inline float hi16f(unsigned u) {
  return __uint_as_float(u & 0xFFFF0000u);
}
__device__ inline sh8 mk8(unsigned a, unsigned b, unsigned c, unsigned d) {
  union { unsigned u[4]; sh8 s; } t;
  t.u[0] = a; t.u[1] = b; t.u[2] = c; t.u[3] = d;
  return t.s;
}

// ---------------------------------------------------------------------------
// fused: grid = ceil(nrows/128) blocks x 256 threads. LDS 64KB (2 regions).
// ---------------------------------------------------------------------------
__global__ __launch_bounds__(256, 2) void fused_kernel(
    const float* __restrict__ phases,
    const float* __restrict__ xr,
    const float* __restrict__ xi,
    float* __restrict__ out_re,
    float* __restrict__ out_im,           // null -> real-only
    unsigned* __restrict__ ctrl,          // [0]=ticket [1]=flag (memset 0)
    unsigned short* __restrict__ Wg,      // 32KB: S3 spill, then W split
    long nrows) {
  __shared__ __align__(16) float2 sA[PSIZE * PSIZE];  // 32 KB
  __shared__ __align__(16) float2 sB[PSIZE * PSIZE];  // 32 KB
  __shared__ unsigned s_ticket;
  unsigned short* sW = (unsigned short*)sA;           // apply-phase alias

  const int tid = threadIdx.x;
  if (tid == 0) s_ticket = atomicAdd(&ctrl[0], 1u);
  __syncthreads();

  if (s_ticket == 0) {
    // ------------------------- builder -------------------------
    const int wv = tid >> 6, lane = tid & 63;

    // Phase A: weight grid (64 layers x 64 slots; li=63 & pads = identity).
    for (int idx = tid; idx < PSIZE * PSIZE; idx += 256) {
      const int li = idx >> 6, m = idx & 63;
      float2 w = make_float2(1.0f, 0.0f);
      if (li < NLAYER && m <= li) {
        const float th = phases[(li * (li + 1)) / 2 + m];
        w = make_float2(LOSS_AMP * cosf(th), LOSS_AMP * sinf(th));
      }
      sA[idx] = w;
    }
    __syncthreads();

    // Phase B: wave wv evolves S_wv = product of layers [16wv, 16wv+16).
    float ure[PSIZE], uim[PSIZE];
#pragma unroll
    for (int r = 0; r < PSIZE; ++r) {
      ure[r] = (r == lane) ? 1.0f : 0.0f;
      uim[r] = 0.0f;
    }
    for (int l = 0; l < 16; ++l) {
      const float2 w2 = sA[(wv * 16 + l) * 64 + lane];
#pragma unroll
      for (int m = 0; m < NLAYER; ++m) {   // pads wc=1,ws=0: exact no-op
        const float wc = rdlane(w2.x, m);
        const float ws = rdlane(w2.y, m);
        const float are = ure[m], aim = uim[m];
        const float bre = ure[m + 1], bim = uim[m + 1];
        ure[m]     = fmaf(wc, are, -ws * bim);
        uim[m]     = fmaf(wc, aim,  ws * bre);
        ure[m + 1] = fmaf(wc, bre, -ws * aim);
        uim[m + 1] = fmaf(wc, bim,  ws * are);
      }
    }
    __syncthreads();   // all grid reads done

    // S3 -> global spill (same-block RAW; barrier drains vmcnt);
    // S0 -> sA (grid dead), S1 -> sB. S2 stays in wave 2's registers.
    if (wv == 3) {
#pragma unroll
      for (int r = 0; r < PSIZE; ++r)
        ((float2*)Wg)[r * 64 + lane] = make_float2(ure[r], uim[r]);
    }
    if (wv == 0) {
#pragma unroll
      for (int r = 0; r < PSIZE; ++r)
        sA[r * 64 + lane] = make_float2(ure[r], uim[r]);
    }
    if (wv == 1) {
#pragma unroll
      for (int r = 0; r < PSIZE; ++r)
        sB[r * 64 + lane] = make_float2(ure[r], uim[r]);
    }
    __syncthreads();

    // Combine 1: P = S1(sB) * S0(sA); wave owns rows [16wv,16wv+16).
    float pre[16], pim[16];
#pragma unroll
    for (int r = 0; r < 16; ++r) { pre[r] = 0.f; pim[r] = 0.f; }
    for (int m = 0; m < PSIZE; ++m) {
      const float2 b = sA[m * 64 + lane];            // per-lane
#pragma unroll
      for (int r = 0; r < 16; ++r) {
        const float2 a = sB[(wv * 16 + r) * 64 + m]; // broadcast
        pre[r] = fmaf(a.x, b.x, fmaf(-a.y, b.y, pre[r]));
        pim[r] = fmaf(a.x, b.y, fmaf( a.y, b.x, pim[r]));
      }
    }
    __syncthreads();
    if (wv == 2) {                                   // S2 -> sA (S0 dead)
#pragma unroll
      for (int r = 0; r < PSIZE; ++r)
        sA[r * 64 + lane] = make_float2(ure[r], uim[r]);
    }
#pragma unroll
    for (int r = 0; r < 16; ++r)                     // P -> sB (S1 dead)
      sB[(wv * 16 + r) * 64 + lane] = make_float2(pre[r], pim[r]);
    __syncthreads();

    // Combine 2: T = S2(sA) * P(sB).
#pragma unroll
    for (int r = 0; r < 16; ++r) { pre[r] = 0.f; pim[r] = 0.f; }
    for (int m = 0; m < PSIZE; ++m) {
      const float2 b = sB[m * 64 + lane];
#pragma unroll
      for (int r = 0; r < 16; ++r) {
        const float2 a = sA[(wv * 16 + r) * 64 + m];
        pre[r] = fmaf(a.x, b.x, fmaf(-a.y, b.y, pre[r]));
        pim[r] = fmaf(a.x, b.y, fmaf( a.y, b.x, pim[r]));
      }
    }
    __syncthreads();
#pragma unroll
    for (int r = 0; r < 16; ++r)                     // T -> sB (P dead)
      sB[(wv * 16 + r) * 64 + lane] = make_float2(pre[r], pim[r]);
    for (int idx = tid; idx < PSIZE * PSIZE; idx += 256)  // S3 -> sA
      sA[idx] = ((const float2*)Wg)[idx];
    __syncthreads();

    // Combine 3: U = S3(sA) * T(sB) -> fre/fim (rows 16wv..+16, col=lane).
    float fre[16], fim[16];
#pragma unroll
    for (int r = 0; r < 16; ++r) { fre[r] = 0.f; fim[r] = 0.f; }
    for (int m = 0; m < PSIZE; ++m) {
      const float2 b = sB[m * 64 + lane];
#pragma unroll
      for (int r = 0; r < 16; ++r) {
        const float2 a = sA[(wv * 16 + r) * 64 + m];
        fre[r] = fmaf(a.x, b.x, fmaf(-a.y, b.y, fre[r]));
        fim[r] = fmaf(a.x, b.y, fmaf( a.y, b.x, fim[r]));
      }
    }
    __syncthreads();   // sA/sB reads done

    // bf16 split W -> sW (LDS): W[mat][n][k] = U-split[n][k], n=U row,
    // k = lane; 16B k-slots XOR-swizzled by (n&7) (R10-verified layout).
    const int slot = lane >> 3, kin = lane & 7;
#pragma unroll
    for (int r = 0; r < 16; ++r) {
      const int n = wv * 16 + r;
      const int base = n * 64 + ((slot ^ (n & 7)) << 3) + kin;
      const unsigned short rh = f32_to_bf16_rn(fre[r]);
      const unsigned short rl = f32_to_bf16_rn(fre[r] - bf16_to_f32(rh));
      const unsigned short ih = f32_to_bf16_rn(fim[r]);
      const unsigned short il = f32_to_bf16_rn(fim[r] - bf16_to_f32(ih));
      sW[0 * 4096 + base] = rh;
      sW[1 * 4096 + base] = rl;
      sW[2 * 4096 + base] = ih;
      sW[3 * 4096 + base] = il;
    }
    __syncthreads();
    // Linear coalesced copy sW -> Wg (S3 spill dead).
    {
      const float4* s4 = (const float4*)sW;
      float4* d4 = (float4*)Wg;
      for (int i = tid; i < WSPLIT_BYTES / 16; i += 256) d4[i] = s4[i];
    }
    __syncthreads();   // drains vmcnt: all Wg stores complete in L2
    __threadfence();   // belt & suspenders (release below also flushes)
    if (tid == 0)
      __hip_atomic_store(&ctrl[1], 1u, __ATOMIC_RELEASE,
                         __HIP_MEMORY_SCOPE_AGENT);
    // sW already populated -> fall through to apply.
  } else {
    // ------------------------- reader -------------------------
    if (tid == 0) {
      while (__hip_atomic_load(&ctrl[1], __ATOMIC_RELAXED,
                               __HIP_MEMORY_SCOPE_AGENT) == 0u)
        __builtin_amdgcn_s_sleep(16);
    }
    __syncthreads();
    // Per-thread agent acquire: invalidates stale L1/L2 before W loads.
    (void)__hip_atomic_load(&ctrl[1], __ATOMIC_ACQUIRE,
                            __HIP_MEMORY_SCOPE_AGENT);
    {
      const float4* src = (const float4*)Wg;
      float4* dst = (float4*)sW;
      for (int i = tid; i < WSPLIT_BYTES / 16; i += 256) dst[i] = src[i];
    }
    __syncthreads();
  }

  // ---------------- apply (R12/R13-verified math + row clamp) ----------------
  const int lane = threadIdx.x & 63;
  const int wave = threadIdx.x >> 6;
  const int lm = lane & 15;
  const int lg = lane >> 4;
  const long row0 = (long)blockIdx.x * 128 + (long)wave * 32;

  f32x4 accRe[2][4], accIm[2][4];
#pragma unroll
  for (int a = 0; a < 2; ++a)
#pragma unroll
    for (int b = 0; b < 4; ++b) {
      accRe[a][b] = f32x4{0.f, 0.f, 0.f, 0.f};
      accIm[a][b] = f32x4{0.f, 0.f, 0.f, 0.f};
    }

#pragma unroll
  for (int ks = 0; ks < 2; ++ks) {
    sh8 arh[2], arl[2], aih[2], ail[2], anh[2], anl[2];
#pragma unroll
    for (int mt = 0; mt < 2; ++mt) {
      long r = row0 + mt * 16 + lm;
      if (r >= nrows) r = nrows - 1;   // clamp: tail rows computed, not stored
      const float4* pr = (const float4*)(xr + r * PSIZE + ks * 32 + lg * 8);
      const float4* pi = (const float4*)(xi + r * PSIZE + ks * 32 + lg * 8);
      const float4 v0 = pr[0], v1 = pr[1];
      const float4 w0 = pi[0], w1 = pi[1];

      const unsigned rh0 = pkbf16(v0.x, v0.y), rh1 = pkbf16(v0.z, v0.w);
      const unsigned rh2 = pkbf16(v1.x, v1.y), rh3 = pkbf16(v1.z, v1.w);
      const unsigned rl0 = pkbf16(v0.x - lo16f(rh0), v0.y - hi16f(rh0));
      const unsigned rl1 = pkbf16(v0.z - lo16f(rh1), v0.w - hi16f(rh1));
      const unsigned rl2 = pkbf16(v1.x - lo16f(rh2), v1.y - hi16f(rh2));
      const unsigned rl3 = pkbf16(v1.z - lo16f(rh3), v1.w - hi16f(rh3));
      arh[mt] = mk8(rh0, rh1, rh2, rh3);
      arl[mt] = mk8(rl0, rl1, rl2, rl3);

      const unsigned ih0 = pkbf16(w0.x, w0.y), ih1 = pkbf16(w0.z, w0.w);
      const unsigned ih2 = pkbf16(w1.x, w1.y), ih3 = pkbf16(w1.z, w1.w);
      const unsigned il0 = pkbf16(w0.x - lo16f(ih0), w0.y - hi16f(ih0));
      const unsigned il1 = pkbf16(w0.z - lo16f(ih1), w0.w - hi16f(ih1));
      const unsigned il2 = pkbf16(w1.x - lo16f(ih2), w1.y - hi16f(ih2));
      const unsigned il3 = pkbf16(w1.z - lo16f(ih3), w1.w - hi16f(ih3));
      aih[mt] = mk8(ih0, ih1, ih2, ih3);
      ail[mt] = mk8(il0, il1, il2, il3);
      anh[mt] = mk8(ih0 ^ 0x80008000u, ih1 ^ 0x80008000u,
                    ih2 ^ 0x80008000u, ih3 ^ 0x80008000u);
      anl[mt] = mk8(il0 ^ 0x80008000u, il1 ^ 0x80008000u,
                    il2 ^ 0x80008000u, il3 ^ 0x80008000u);
    }

#pragma unroll
    for (int nt = 0; nt < 4; ++nt) {
      const int n = nt * 16 + lm;
      const int sidx = n * 64 + (((ks * 4 + lg) ^ (n & 7)) << 3);
      const sh8 bRh = *(const sh8*)&sW[0 * 4096 + sidx];
      const sh8 bRl = *(const sh8*)&sW[1 * 4096 + sidx];
      const sh8 bIh = *(const sh8*)&sW[2 * 4096 + sidx];
      const sh8 bIl = *(const sh8*)&sW[3 * 4096 + sidx];
#pragma unroll
      for (int mt = 0; mt < 2; ++mt) {
        f32x4 cr = accRe[mt][nt];
        cr = __builtin_amdgcn_mfma_f32_16x16x32_bf16(arh[mt], bRh, cr, 0, 0, 0);
        cr = __builtin_amdgcn_mfma_f32_16x16x32_bf16(arh[mt], bRl, cr, 0, 0, 0);
        cr = __builtin_amdgcn_mfma_f32_16x16x32_bf16(arl[mt], bRh, cr, 0, 0, 0);
        cr = __builtin_amdgcn_mfma_f32_16x16x32_bf16(anh[mt], bIh, cr, 0, 0, 0);
        cr = __builtin_amdgcn_mfma_f32_16x16x32_bf16(anh[mt], bIl, cr, 0, 0, 0);
        cr = __builtin_amdgcn_mfma_f32_16x16x32_bf16(anl[mt], bIh, cr, 0, 0, 0);
        accRe[mt][nt] = cr;
        f32x4 ci = accIm[mt][nt];
        ci = __builtin_amdgcn_mfma_f32_16x16x32_bf16(arh[mt], bIh, ci, 0, 0, 0);
        ci = __builtin_amdgcn_mfma_f32_16x16x32_bf16(arh[mt], bIl, ci, 0, 0, 0);
        ci = __builtin_amdgcn_mfma_f32_16x16x32_bf16(arl[mt], bIh, ci, 0, 0, 0);
        ci = __builtin_amdgcn_mfma_f32_16x16x32_bf16(aih[mt], bRh, ci, 0, 0, 0);
        ci = __builtin_amdgcn_mfma_f32_16x16x32_bf16(aih[mt], bRl, ci, 0, 0, 0);
        ci = __builtin_amdgcn_mfma_f32_16x16x32_bf16(ail[mt], bRh, ci, 0, 0, 0);
        accIm[mt][nt] = ci;
      }
    }
  }

  // Epilogue: Kerr rotation; guarded stores (64B/16-lane segments).
#pragma unroll
  for (int mt = 0; mt < 2; ++mt) {
#pragma unroll
    for (int reg = 0; reg < 4; ++reg) {
      const long row = row0 + mt * 16 + lg * 4 + reg;
      if (row < nrows) {
#pragma unroll
        for (int nt = 0; nt < 4; ++nt) {
          const int col = nt * 16 + lm;
          const float re = accRe[mt][nt][reg];
          const float im = accIm[mt][nt][reg];
          const float p = NL_COEFF * fmaf(re, re, im * im);
          out_re[row * PSIZE + col] = fmaf(-im, p, re);
          if (out_im != nullptr) out_im[row * PSIZE + col] = fmaf(re, p, im);
        }
      }
    }
  }
}

// ---------------------------------------------------------------------------
// Fallback path (no/small workspace): R13's verified build -> g_U_fallback,
// then the VALU tail over all rows.
// ---------------------------------------------------------------------------
__global__ __launch_bounds__(512, 1) void build_kernel(
    const float* __restrict__ phases) {
  __shared__ float2 sS[3][PSIZE * PSIZE];
  __shared__ float2 sWsm[PSIZE * PSIZE];
  const int tid = threadIdx.x;
  const int wv = tid >> 6;
  const int lane = tid & 63;

  for (int idx = tid; idx < PSIZE * PSIZE; idx += 512) {
    const int li = idx >> 6, m = idx & 63;
    float2 w = make_float2(1.0f, 0.0f);
    if (li < NLAYER && m <= li) {
      const float th = phases[(li * (li + 1)) / 2 + m];
      w = make_float2(LOSS_AMP * cosf(th), LOSS_AMP * sinf(th));
    }
    sWsm[idx] = w;
  }
  __syncthreads();

  float ure[PSIZE], uim[PSIZE];
  if (wv < 4) {
#pragma unroll
    for (int r = 0; r < PSIZE; ++r) {
      ure[r] = (r == lane) ? 1.0f : 0.0f;
      uim[r] = 0.0f;
    }
    for (int l = 0; l < 16; ++l) {
      const float2 w2 = sWsm[(wv * 16 + l) * 64 + lane];
#pragma unroll
      for (int m = 0; m < NLAYER; ++m) {
        const float wc = rdlane(w2.x, m);
        const float ws = rdlane(w2.y, m);
        const float are = ure[m], aim = uim[m];
        const float bre = ure[m + 1], bim = uim[m + 1];
        ure[m]     = fmaf(wc, are, -ws * bim);
        uim[m]     = fmaf(wc, aim,  ws * bre);
        ure[m + 1] = fmaf(wc, bre, -ws * aim);
        uim[m + 1] = fmaf(wc, bim,  ws * are);
      }
    }
  }
  __syncthreads();
  if (wv < 4) {
    float2* dst = (wv == 3) ? sWsm : sS[wv];
#pragma unroll
    for (int r = 0; r < PSIZE; ++r)
      dst[r * 64 + lane] = make_float2(ure[r], uim[r]);
  }
  __syncthreads();

  const int wg = wv >> 2, w4 = wv & 3;
  {
    const float2* A  = (wg == 0) ? sS[1] : sWsm;
    const float2* Bm = (wg == 0) ? sS[0] : sS[2];
    float pre[16], pim[16];
#pragma unroll
    for (int r = 0; r < 16; ++r) { pre[r] = 0.f; pim[r] = 0.f; }
    for (int m = 0; m < PSIZE; ++m) {
      const float2 b = Bm[m * 64 + lane];
#pragma unroll
      for (int r = 0; r < 16; ++r) {
        const float2 a = A[(16 * w4 + r) * 64 + m];
        pre[r] = fmaf(a.x, b.x, fmaf(-a.y, b.y, pre[r]));
        pim[r] = fmaf(a.x, b.y, fmaf( a.y, b.x, pim[r]));
      }
    }
    __syncthreads();
    float2* Pd = (wg == 0) ? sS[0] : sS[1];
#pragma unroll
    for (int r = 0; r < 16; ++r)
      Pd[(16 * w4 + r) * 64 + lane] = make_float2(pre[r], pim[r]);
  }
  __syncthreads();

  float fre[8], fim[8];
#pragma unroll
  for (int r = 0; r < 8; ++r) { fre[r] = 0.f; fim[r] = 0.f; }
  for (int m = 0; m < PSIZE; ++m) {
    const float2 b = sS[0][m * 64 + lane];
#pragma unroll
    for (int r = 0; r < 8; ++r) {
      const float2 a = sS[1][(8 * wv + r) * 64 + m];
      fre[r] = fmaf(a.x, b.x, fmaf(-a.y, b.y, fre[r]));
      fim[r] = fmaf(a.x, b.y, fmaf( a.y, b.x, fim[r]));
    }
  }
#pragma unroll
  for (int r = 0; r < 8; ++r)
    ((float2*)g_U_fallback)[(8 * wv + r) * 64 + lane] =
        make_float2(fre[r], fim[r]);
}

__global__ __launch_bounds__(256, 2) void tail_kernel(
    const float* __restrict__ xr,
    const float* __restrict__ xi,
    float* __restrict__ out_re,
    float* __restrict__ out_im,
    long nrows) {
  __shared__ __align__(16) float sU[2 * PSIZE * PSIZE];
  {
    const float4* g4 = (const float4*)g_U_fallback;
    float4* s4 = (float4*)sU;
    for (int i = threadIdx.x; i < (2 * PSIZE * PSIZE) / 4; i += 256)
      s4[i] = g4[i];
  }
  __syncthreads();

  const long row = (long)blockIdx.x * 256 + threadIdx.x;
  if (row >= nrows) return;

  const float4* xr4 = (const float4*)(xr + (size_t)row * PSIZE);
  const float4* xi4 = (const float4*)(xi + (size_t)row * PSIZE);

  float aR[PSIZE], aI[PSIZE];
#pragma unroll
  for (int j = 0; j < PSIZE; ++j) { aR[j] = 0.0f; aI[j] = 0.0f; }

  const float4* su4 = (const float4*)sU;

#pragma unroll 1
  for (int kc = 0; kc < 8; ++kc) {
    const float4 a0 = xr4[2 * kc];
    const float4 a1 = xr4[2 * kc + 1];
    const float4 b0 = xi4[2 * kc];
    const float4 b1 = xi4[2 * kc + 1];
    const float4* up = su4 + kc * 4;
#pragma unroll
    for (int j = 0; j < PSIZE; ++j) {
      const float4 u0 = up[j * 32 + 0];
      const float4 u1 = up[j * 32 + 1];
      const float4 u2 = up[j * 32 + 2];
      const float4 u3 = up[j * 32 + 3];
      float r = aR[j], m = aI[j];
      r = fmaf(a0.x, u0.x, r); r = fmaf(-b0.x, u0.y, r);
      m = fmaf(a0.x, u0.y, m); m = fmaf( b0.x, u0.x, m);
      r = fmaf(a0.y, u0.z, r); r = fmaf(-b0.y, u0.w, r);
      m = fmaf(a0.y, u0.w, m); m = fmaf( b0.y, u0.z, m);
      r = fmaf(a0.z, u1.x, r); r = fmaf(-b0.z, u1.y, r);
      m = fmaf(a0.z, u1.y, m); m = fmaf( b0.z, u1.x, m);
      r = fmaf(a0.w, u1.z, r); r = fmaf(-b0.w, u1.w, r);
      m = fmaf(a0.w, u1.w, m); m = fmaf( b0.w, u1.z, m);
      r = fmaf(a1.x, u2.x, r); r = fmaf(-b1.x, u2.y, r);
      m = fmaf(a1.x, u2.y, m); m = fmaf( b1.x, u2.x, m);
      r = fmaf(a1.y, u2.z, r); r = fmaf(-b1.y, u2.w, r);
      m = fmaf(a1.y, u2.w, m); m = fmaf( b1.y, u2.z, m);
      r = fmaf(a1.z, u3.x, r); r = fmaf(-b1.z, u3.y, r);
      m = fmaf(a1.z, u3.y, m); m = fmaf( b1.z, u3.x, m);
      r = fmaf(a1.w, u3.z, r); r = fmaf(-b1.w, u3.w, r);
      m = fmaf(a1.w, u3.w, m); m = fmaf( b1.w, u3.z, m);
      aR[j] = r; aI[j] = m;
    }
  }

  float* orp = out_re + (size_t)row * PSIZE;
  float* oip = (out_im != nullptr) ? (out_im + (size_t)row * PSIZE) : nullptr;
#pragma unroll
  for (int jq = 0; jq < 16; ++jq) {
    const int j = 4 * jq;
    float4 vr, vi;
    {
      const float p = NL_COEFF * fmaf(aR[j], aR[j], aI[j] * aI[j]);
      vr.x = fmaf(-aI[j], p, aR[j]); vi.x = fmaf(aR[j], p, aI[j]);
    }
    {
      const float p = NL_COEFF * fmaf(aR[j+1], aR[j+1], aI[j+1] * aI[j+1]);
      vr.y = fmaf(-aI[j+1], p, aR[j+1]); vi.y = fmaf(aR[j+1], p, aI[j+1]);
    }
    {
      const float p = NL_COEFF * fmaf(aR[j+2], aR[j+2], aI[j+2] * aI[j+2]);
      vr.z = fmaf(-aI[j+2], p, aR[j+2]); vi.z = fmaf(aR[j+2], p, aI[j+2]);
    }
    {
      const float p = NL_COEFF * fmaf(aR[j+3], aR[j+3], aI[j+3] * aI[j+3]);
      vr.w = fmaf(-aI[j+3], p, aR[j+3]); vi.w = fmaf(aR[j+3], p, aI[j+3]);
    }
    ((float4*)orp)[jq] = vr;
    if (oip != nullptr) ((float4*)oip)[jq] = vi;
  }
}

extern "C" void kernel_launch(void* const* d_in, const int* in_sizes, int n_in,
                              void* d_out, int out_size, void* d_ws, size_t ws_size,
                              hipStream_t stream) {
  // Identify inputs by size, not position: phases has exactly 2016 elements.
  int pidx = -1;
  for (int i = 0; i < n_in; ++i) {
    if (in_sizes[i] == N_PHASES) { pidx = i; break; }
  }
  if (pidx < 0) pidx = 2;
  int xa = -1, xb = -1;
  for (int i = 0; i < n_in; ++i) {
    if (i == pidx) continue;
    if (xa < 0) xa = i;
    else if (xb < 0) xb = i;
  }
  if (xa < 0 || xb < 0) return;

  const float* phases = (const float*)d_in[pidx];
  const float* x_real = (const float*)d_in[xa];
  const float* x_imag = (const float*)d_in[xb];

  long b_in = (long)in_sizes[xa] / PSIZE;
  if ((long)in_sizes[xb] / PSIZE < b_in) b_in = (long)in_sizes[xb] / PSIZE;

  float* out = (float*)d_out;
  float* out_re = out;
  float* out_im = nullptr;
  long nrows;

  if ((long)out_size >= 2 * b_in * PSIZE) {
    const long half = (long)out_size / 2;     // planar [re | im]
    out_im = out + half;
    long cap = half / PSIZE;
    nrows = (b_in < cap) ? b_in : cap;
  } else {
    long cap = (long)out_size / PSIZE;        // real-part-only
    nrows = (b_in < cap) ? b_in : cap;
  }
  if (nrows <= 0) return;

  if (d_ws != nullptr && ws_size >= (size_t)FUSED_WS_NEED) {
    hipMemsetAsync(d_ws, 0, CTRL_BYTES, stream);  // zero ticket+flag per launch
    unsigned* ctrl = (unsigned*)d_ws;
    unsigned short* Wg = (unsigned short*)((char*)d_ws + CTRL_BYTES);
    const int nblocks = (int)((nrows + 127) / 128);
    fused_kernel<<<nblocks, 256, 0, stream>>>(phases, x_real, x_imag,
                                              out_re, out_im, ctrl, Wg, nrows);
  } else {
    build_kernel<<<1, 512, 0, stream>>>(phases);
    const int tblocks = (int)((nrows + 255) / 256);
    tail_kernel<<<tblocks, 256, 0, stream>>>(x_real, x_imag,
                                             out_re, out_im, nrows);
  }
}